// Round 8
// baseline (203.704 us; speedup 1.0000x reference)
//
#include <hip/hip_runtime.h>

#define NB_B 2
#define NB_E 1024
#define NB_DM 512
#define NB_H 8

typedef __attribute__((ext_vector_type(8))) __bf16 bf16x8;
typedef __attribute__((ext_vector_type(8))) unsigned short u16x8;
typedef __attribute__((ext_vector_type(4))) float f32x4;

static __device__ __forceinline__ float bf2f(unsigned short u){
  union { unsigned int i; float f; } v; v.i = ((unsigned int)u) << 16; return v.f;
}
static __device__ __forceinline__ unsigned short f2bf(float f){
  union { float f; unsigned int i; } v; v.f = f;
  unsigned int r = v.i + 0x7FFFu + ((v.i >> 16) & 1u);
  return (unsigned short)(r >> 16);
}
static __device__ __forceinline__ f32x4 mfma16(bf16x8 a, bf16x8 b, f32x4 c){
  return __builtin_amdgcn_mfma_f32_16x16x32_bf16(a, b, c, 0, 0, 0);
}
static __device__ __forceinline__ float fast_exp2(float x){
#if __has_builtin(__builtin_amdgcn_exp2f)
  return __builtin_amdgcn_exp2f(x);
#else
  return exp2f(x);
#endif
}

// ---- transpose x [B,DM,E] (f32) -> s_bf [B,E,DM] (bf16) ----
__global__ void k_transpose_x(const float* __restrict__ x, unsigned short* __restrict__ s_bf){
  __shared__ float tile[32][33];
  const int b = blockIdx.z;
  const int d0 = blockIdx.y * 32;
  const int e0 = blockIdx.x * 32;
  const int tx = threadIdx.x, ty = threadIdx.y;
  #pragma unroll
  for (int r = 0; r < 4; ++r){
    const int d = d0 + ty + r*8;
    tile[ty + r*8][tx] = x[((size_t)b*NB_DM + d)*NB_E + e0 + tx];
  }
  __syncthreads();
  #pragma unroll
  for (int r = 0; r < 4; ++r){
    const int e = e0 + ty + r*8;
    s_bf[((size_t)b*NB_E + e)*NB_DM + d0 + tx] = f2bf(tile[tx][ty + r*8]);
  }
}

// ---- transpose 4 weights [512,512] f32 -> wT bf16 [which][n][k] ----
__global__ void k_transpose_w(const float* __restrict__ w0, const float* __restrict__ w1,
                              const float* __restrict__ w2, const float* __restrict__ w3,
                              unsigned short* __restrict__ wT){
  __shared__ float tile[32][33];
  const int which = blockIdx.z;
  const float* w = which==0 ? w0 : which==1 ? w1 : which==2 ? w2 : w3;
  unsigned short* dst = wT + (size_t)which*512*512;
  const int k0 = blockIdx.y*32, n0 = blockIdx.x*32;
  const int tx = threadIdx.x, ty = threadIdx.y;
  #pragma unroll
  for (int r = 0; r < 4; ++r)
    tile[ty + r*8][tx] = w[(size_t)(k0 + ty + r*8)*512 + n0 + tx];
  __syncthreads();
  #pragma unroll
  for (int r = 0; r < 4; ++r)
    dst[(size_t)(n0 + ty + r*8)*512 + k0 + tx] = f2bf(tile[tx][ty + r*8]);
}

// ---- layernorm rows of s_bf -> qn_bf (4 rows per 256-thread block) ----
__global__ __launch_bounds__(256) void k_ln(const unsigned short* __restrict__ s_bf,
    unsigned short* __restrict__ qn_bf, const float* __restrict__ gg, const float* __restrict__ bb){
  const int row = blockIdx.x*4 + (threadIdx.x >> 6);
  const int l = threadIdx.x & 63;
  const unsigned short* sp = s_bf + (size_t)row*512 + l*8;
  u16x8 v = *(const u16x8*)sp;
  float f[8]; float sum = 0.f, sq = 0.f;
  #pragma unroll
  for (int i = 0; i < 8; ++i){ f[i] = bf2f(v[i]); sum += f[i]; sq += f[i]*f[i]; }
  #pragma unroll
  for (int off = 32; off >= 1; off >>= 1){
    sum += __shfl_xor(sum, off);
    sq  += __shfl_xor(sq, off);
  }
  const float mu  = sum * (1.f/512.f);
  const float var = sq * (1.f/512.f) - mu*mu;
  const float rstd = rsqrtf(var + 1e-6f);
  const float4 g0 = *(const float4*)(gg + l*8);
  const float4 g1 = *(const float4*)(gg + l*8 + 4);
  const float4 b0 = *(const float4*)(bb + l*8);
  const float4 b1 = *(const float4*)(bb + l*8 + 4);
  const float gv[8] = {g0.x,g0.y,g0.z,g0.w,g1.x,g1.y,g1.z,g1.w};
  const float bv[8] = {b0.x,b0.y,b0.z,b0.w,b1.x,b1.y,b1.z,b1.w};
  u16x8 o;
  #pragma unroll
  for (int i = 0; i < 8; ++i) o[i] = f2bf((f[i]-mu)*rstd*gv[i] + bv[i]);
  *(u16x8*)(qn_bf + (size_t)row*512 + l*8) = o;
}

// ---- classify dist -> uint8 (0..5 = rpr class, 6 = masked) + column counts ----
__global__ __launch_bounds__(256) void k_dist(const int* __restrict__ dist,
    unsigned char* __restrict__ d8, int* __restrict__ cnt){
  const int b = blockIdx.y;
  const int i0 = blockIdx.x * 16;
  const int t = threadIdx.x;
  int c0 = 0, c1 = 0, c2 = 0, c3 = 0;
  #pragma unroll 4
  for (int r = 0; r < 16; ++r){
    const int row = i0 + r;
    const int4 d = ((const int4*)(dist + ((size_t)b*NB_E + row)*NB_E))[t];
    uchar4 o;
    o.x = (unsigned char)(d.x <= 5 ? d.x : 6);
    o.y = (unsigned char)(d.y <= 5 ? d.y : 6);
    o.z = (unsigned char)(d.z <= 5 ? d.z : 6);
    o.w = (unsigned char)(d.w <= 5 ? d.w : 6);
    ((uchar4*)(d8 + ((size_t)b*NB_E + row)*NB_E))[t] = o;
    c0 += (d.x <= 5); c1 += (d.y <= 5); c2 += (d.z <= 5); c3 += (d.w <= 5);
  }
  int* cb = cnt + b*NB_E + t*4;
  atomicAdd(cb + 0, c0);
  atomicAdd(cb + 1, c1);
  atomicAdd(cb + 2, c2);
  atomicAdd(cb + 3, c3);
}

// ---- fused QKV GEMM: z=0 -> Q (scaled 1/8, + qr table), z=1 -> K, z=2 -> V^T ----
__global__ __launch_bounds__(256, 4) void k_gemm_qkv(
    const unsigned short* __restrict__ qn, const unsigned short* __restrict__ s,
    const unsigned short* __restrict__ wT, const float* __restrict__ base_rpr,
    unsigned short* __restrict__ Qb, unsigned short* __restrict__ Kb,
    unsigned short* __restrict__ VTb, float* __restrict__ qr)
{
  const int z = blockIdx.z;
  const unsigned short* A  = (z == 0) ? qn : s;
  const unsigned short* BT = wT + (size_t)z*262144;
  const int tid = threadIdx.x;
  const int l = tid & 63, wv = tid >> 6;
  const int ll = l & 15, lg = l >> 4;
  const int m0 = blockIdx.x*64 + wv*16;
  const int n0 = blockIdx.y*64;
  const unsigned short* arow = A + (size_t)(m0 + ll)*512 + lg*8;
  const unsigned short* brow = BT + (size_t)(n0 + ll)*512 + lg*8;
  f32x4 acc[4];
  #pragma unroll
  for (int nt = 0; nt < 4; ++nt) acc[nt] = (f32x4){0.f,0.f,0.f,0.f};
  bf16x8 a_c = *(const bf16x8*)(arow);
  bf16x8 b_c[4];
  #pragma unroll
  for (int nt = 0; nt < 4; ++nt) b_c[nt] = *(const bf16x8*)(brow + (size_t)nt*8192);
  #pragma unroll
  for (int ks = 0; ks < 16; ++ks){
    const int kn = (ks + 1) & 15;
    bf16x8 a_n = *(const bf16x8*)(arow + kn*32);
    bf16x8 b_n[4];
    #pragma unroll
    for (int nt = 0; nt < 4; ++nt) b_n[nt] = *(const bf16x8*)(brow + (size_t)nt*8192 + kn*32);
    #pragma unroll
    for (int nt = 0; nt < 4; ++nt) acc[nt] = mfma16(a_c, b_c[nt], acc[nt]);
    a_c = a_n;
    #pragma unroll
    for (int nt = 0; nt < 4; ++nt) b_c[nt] = b_n[nt];
  }
  const int rbase = m0 + lg*4;
  const int bidx = rbase >> 10;
  const int e = rbase & 1023;
  const int h = n0 >> 6;
  if (z == 0){
    float rprv[6][4];
    #pragma unroll
    for (int c = 0; c < 6; ++c)
      #pragma unroll
      for (int nt = 0; nt < 4; ++nt)
        rprv[c][nt] = base_rpr[c*64 + nt*16 + ll];
    #pragma unroll
    for (int nt = 0; nt < 4; ++nt){
      const int dk = nt*16 + ll;
      unsigned short* dp = Qb + (((size_t)bidx*NB_H + h)*NB_E + e)*64 + dk;
      #pragma unroll
      for (int r = 0; r < 4; ++r)
        dp[(size_t)r*64] = f2bf(acc[nt][r]*0.125f);
    }
    #pragma unroll
    for (int r = 0; r < 4; ++r){
      #pragma unroll
      for (int c = 0; c < 6; ++c){
        float tv = 0.f;
        #pragma unroll
        for (int nt = 0; nt < 4; ++nt) tv += acc[nt][r]*0.125f*rprv[c][nt];
        tv += __shfl_xor(tv, 1);
        tv += __shfl_xor(tv, 2);
        tv += __shfl_xor(tv, 4);
        tv += __shfl_xor(tv, 8);
        if (ll == 0)
          qr[(((size_t)(bidx*NB_H + h)*NB_E) + e + r)*8 + c] = tv;
      }
    }
  } else if (z == 1){
    #pragma unroll
    for (int nt = 0; nt < 4; ++nt){
      const int dk = nt*16 + ll;
      unsigned short* dp = Kb + (((size_t)bidx*NB_H + h)*NB_E + e)*64 + dk;
      #pragma unroll
      for (int r = 0; r < 4; ++r)
        dp[(size_t)r*64] = f2bf(acc[nt][r]);
    }
  } else {
    #pragma unroll
    for (int nt = 0; nt < 4; ++nt){
      const int dv = nt*16 + ll;
      ushort4 ov;
      ov.x = f2bf(acc[nt][0]); ov.y = f2bf(acc[nt][1]);
      ov.z = f2bf(acc[nt][2]); ov.w = f2bf(acc[nt][3]);
      *(ushort4*)(VTb + (((size_t)bidx*NB_H + h)*64 + dv)*NB_E + e) = ov;
    }
  }
}

// ---- FC GEMM: x_out f32 [B,DM,E] = outb @ w_fc^T + residual; 16x32 wave tiles ----
__global__ __launch_bounds__(256, 4) void k_fc(
    const unsigned short* __restrict__ A, const unsigned short* __restrict__ BT,
    float* __restrict__ dst_f, const float* __restrict__ resid)
{
  const int tid = threadIdx.x;
  const int l = tid & 63, wv = tid >> 6;
  const int ll = l & 15, lg = l >> 4;
  const int m0 = blockIdx.x*64 + wv*16;
  const int n0 = blockIdx.y*32;
  const unsigned short* arow = A + (size_t)(m0 + ll)*512 + lg*8;
  const unsigned short* brow = BT + (size_t)(n0 + ll)*512 + lg*8;
  f32x4 acc[2];
  acc[0] = (f32x4){0.f,0.f,0.f,0.f};
  acc[1] = (f32x4){0.f,0.f,0.f,0.f};
  bf16x8 a_c = *(const bf16x8*)(arow);
  bf16x8 b_c0 = *(const bf16x8*)(brow);
  bf16x8 b_c1 = *(const bf16x8*)(brow + 8192);
  #pragma unroll
  for (int ks = 0; ks < 16; ++ks){
    const int kn = (ks + 1) & 15;
    bf16x8 a_n  = *(const bf16x8*)(arow + kn*32);
    bf16x8 b_n0 = *(const bf16x8*)(brow + kn*32);
    bf16x8 b_n1 = *(const bf16x8*)(brow + 8192 + kn*32);
    acc[0] = mfma16(a_c, b_c0, acc[0]);
    acc[1] = mfma16(a_c, b_c1, acc[1]);
    a_c = a_n; b_c0 = b_n0; b_c1 = b_n1;
  }
  const int rbase = m0 + lg*4;
  const int bidx = rbase >> 10;
  const int e = rbase & 1023;
  #pragma unroll
  for (int nt = 0; nt < 2; ++nt){
    const int n = n0 + nt*16 + ll;
    const float* xr = resid + ((size_t)bidx*NB_DM + n)*NB_E + e;
    const float4 rv = *(const float4*)xr;
    const float4 ov = make_float4(acc[nt][0]+rv.x, acc[nt][1]+rv.y,
                                  acc[nt][2]+rv.z, acc[nt][3]+rv.w);
    *(float4*)(dst_f + ((size_t)bidx*NB_DM + n)*NB_E + e) = ov;
  }
}

// ---- fused attention: 1024 blocks x 512 threads (8 waves), 16 q-rows per block.
// Wave w owns j in [w*128, w*128+128). No-max softmax (logits bounded; masked -> 0).
// Tail: waves 0-3 do PV MFMA + outb; waves 4-7 drain P store.
// PHASE<4: ablation probes writing keep-alive to scratch only.
#define D_OFF 2048
#define P_OFF 18432
template<int PHASE, bool WRITE_PG>
__global__ __launch_bounds__(512, 6) void k_attn(
    const unsigned short* __restrict__ Q, const unsigned short* __restrict__ K,
    const unsigned short* __restrict__ VT, const float* __restrict__ qr,
    const unsigned char* __restrict__ d8, float* __restrict__ attn_out,
    unsigned short* __restrict__ Pg, unsigned short* __restrict__ outb,
    float* __restrict__ apeP, float* __restrict__ kscr)
{
  __shared__ __align__(16) unsigned char smem[51200];
  unsigned short* plds = (unsigned short*)(smem + P_OFF);
  float* qr_l = (float*)smem;                 // [0,384)
  float* reds = (float*)(smem + 512);         // [512,1024): 8 waves x 16 rows

  const int tid = threadIdx.x;
  const int l = tid & 63, w = tid >> 6;       // 8 waves
  const int lg = l >> 4, ll = l & 15;
  const int n = blockIdx.x;
  const int m = n >> 3;
  const int bh = (n & 7)*2 + (m >> 6);        // b*H + h  (XCD-locality decode)
  const int b = bh >> 3;
  const int it = m & 63;
  const int ib = it << 4;
  const int j0 = w << 7;                      // 128 cols per wave

  // d8 tile -> LDS (16KB): 2 x int4 per thread
  const unsigned char* d8g = d8 + ((size_t)b*NB_E + ib)*NB_E;
  int4 dr0 = ((const int4*)d8g)[tid];
  int4 dr1 = ((const int4*)(d8g + 8192))[tid];
  asm volatile("" :: "v"(dr0.x), "v"(dr1.x));  // keep loads live in ablation phases
  ((int4*)(smem + D_OFF))[tid] = dr0;
  ((int4*)(smem + D_OFF + 8192))[tid] = dr1;

  if (tid < 96)
    qr_l[tid] = qr[((size_t)bh*NB_E + ib + (tid/6))*8 + (tid % 6)];

  const unsigned short* Qbp = Q + ((size_t)bh*NB_E + ib)*64;
  bf16x8 qf0 = *(const bf16x8*)(Qbp + (size_t)ll*64 + lg*8);
  bf16x8 qf1 = *(const bf16x8*)(Qbp + (size_t)ll*64 + 32 + lg*8);

  // S = (Q/8) K^T over this wave's 128 cols
  f32x4 s[8];
  const unsigned short* Kb = K + (size_t)bh*NB_E*64;
  #pragma unroll
  for (int jt = 0; jt < 8; ++jt){
    const size_t krow = (size_t)(j0 + jt*16 + ll)*64;
    bf16x8 k0 = *(const bf16x8*)(Kb + krow + lg*8);
    bf16x8 k1 = *(const bf16x8*)(Kb + krow + 32 + lg*8);
    f32x4 acc = {0.f,0.f,0.f,0.f};
    acc = mfma16(qf0, k0, acc);
    acc = mfma16(qf1, k1, acc);
    s[jt] = acc;
  }
  __syncthreads();

  if (PHASE == 1){
    float t = 0.f;
    #pragma unroll
    for (int jt = 0; jt < 8; ++jt)
      #pragma unroll
      for (int r = 0; r < 4; ++r) t += s[jt][r];
    kscr[(n & 63)*1024 + tid] = t;
    return;
  }

  // bias + exp + row-sum (no max subtraction: logits bounded, masked -> exactly 0)
  float rsum[4] = {0.f, 0.f, 0.f, 0.f};
  #pragma unroll
  for (int jt = 0; jt < 8; ++jt){
    const int j = j0 + jt*16 + ll;
    #pragma unroll
    for (int r = 0; r < 4; ++r){
      const int il = lg*4 + r;
      const unsigned char c = smem[D_OFF + il*1024 + j];
      const float p = (c < 6)
        ? fast_exp2((s[jt][r] + qr_l[il*6 + c]) * 1.4426950408889634f) : 0.f;
      s[jt][r] = p;
      rsum[r] += p;
    }
  }
  #pragma unroll
  for (int r = 0; r < 4; ++r){
    float sum = rsum[r];
    sum += __shfl_xor(sum, 1);
    sum += __shfl_xor(sum, 2);
    sum += __shfl_xor(sum, 4);
    sum += __shfl_xor(sum, 8);
    if (ll == 0) reds[w*16 + lg*4 + r] = sum;
  }
  __syncthreads();
  float rinv[4];
  #pragma unroll
  for (int r = 0; r < 4; ++r){
    const int il = lg*4 + r;
    float tot = 0.f;
    #pragma unroll
    for (int wv = 0; wv < 8; ++wv) tot += reds[wv*16 + il];
    rinv[r] = 1.0f / (tot + 1e-30f);
  }

  if (PHASE == 2){
    kscr[(n & 63)*1024 + tid] = rinv[0]+rinv[1]+rinv[2]+rinv[3] + s[0][0];
    return;
  }

  // normalize: P -> bf16 LDS (XOR-swizzled) + race-free ape column partials
  float* apeRow = (PHASE == 3) ? (kscr + (n & 63)*1024)
                               : (apeP + (((size_t)bh*64 + it) << 10));
  #pragma unroll
  for (int jt = 0; jt < 8; ++jt){
    const int j = j0 + jt*16 + ll;
    float csum = 0.f;
    #pragma unroll
    for (int r = 0; r < 4; ++r){
      const int il = lg*4 + r;
      const float pn = s[jt][r] * rinv[r];
      const int byo = ((il*1024 + j)*2) ^ ((il & 7) << 4);
      plds[byo >> 1] = f2bf(pn);
      csum += pn;
    }
    csum += __shfl_xor(csum, 16);
    csum += __shfl_xor(csum, 32);
    if (l < 16) apeRow[j0 + jt*16 + l] = csum;
  }
  __syncthreads();

  if (PHASE == 3){
    kscr[(n & 63)*1024 + tid] = (float)plds[tid];   // keep LDS writes + reads live
    return;
  }

  if (w < 4){
    // PV: wave w -> dv chunk [w*16, w*16+16)
    const unsigned short* Vb = VT + ((size_t)bh*64 + w*16 + ll)*NB_E;
    f32x4 o = {0.f,0.f,0.f,0.f};
    #pragma unroll 4
    for (int kk = 0; kk < 32; ++kk){
      bf16x8 vf = *(const bf16x8*)(Vb + kk*32 + lg*8);
      const int byo = ((ll*2048 + (kk*32 + lg*8)*2)) ^ ((ll & 7) << 4);
      bf16x8 p = *(const bf16x8*)(smem + P_OFF + byo);
      o = mfma16(p, vf, o);
    }
    const int coln = (bh & 7)*64 + w*16 + ll;
    #pragma unroll
    for (int r = 0; r < 4; ++r){
      const int e0 = ib + lg*4 + r;
      outb[((size_t)b*NB_E + e0)*512 + coln] = f2bf(o[r]);
    }
  } else {
    // store waves: rows (w-4)*4+lg
    const int il = (w - 4)*4 + lg;
    if (WRITE_PG){
      unsigned short* prow = Pg + (((size_t)bh << 10) + ib + il) * 1024;
      const int rowb = il*2048;
      #pragma unroll
      for (int c2 = 0; c2 < 8; ++c2){
        const int byo = (rowb + c2*256 + ll*16) ^ ((il & 7) << 4);
        const u16x8 pv = *(const u16x8*)(smem + P_OFF + byo);
        *(u16x8*)(prow + c2*128 + ll*8) = pv;
      }
    } else {
      float* arow = attn_out + ((size_t)bh*NB_E + ib + il)*NB_E;
      const int rowb = il*2048;
      #pragma unroll
      for (int c2 = 0; c2 < 16; ++c2){
        const int byo = (rowb + c2*128 + ll*8) ^ ((il & 7) << 4);
        const ushort4 pv = *(const ushort4*)(smem + P_OFF + byo);
        f32x4 ov;
        ov[0] = bf2f(pv.x); ov[1] = bf2f(pv.y); ov[2] = bf2f(pv.z); ov[3] = bf2f(pv.w);
        *(f32x4*)(arow + c2*64 + ll*4) = ov;
      }
    }
  }
}

// ---- expand P bf16 -> attn f32. 2048 blocks, dense per-instruction stores. ----
__global__ __launch_bounds__(256) void k_expand(const unsigned short* __restrict__ Pg,
    float* __restrict__ attn)
{
  const int bh = blockIdx.y;
  const int tile = blockIdx.x;
  const size_t rowbase = ((size_t)bh << 10) + tile*8;
  const unsigned short* src = Pg + (rowbase << 10);
  float* dst = attn + (rowbase << 10);
  const int t = threadIdx.x;
  #pragma unroll
  for (int r = 0; r < 8; ++r){
    const ushort4 v = *(const ushort4*)(src + ((size_t)r << 10) + t*4);
    f32x4 o;
    o[0] = bf2f(v.x); o[1] = bf2f(v.y); o[2] = bf2f(v.z); o[3] = bf2f(v.w);
    *(f32x4*)(dst + ((size_t)r << 10) + t*4) = o;
  }
}

// ---- ape reduce: out[b][j] = sum over 512 partial rows / cnt ----
__global__ __launch_bounds__(256) void k_apered(const float* __restrict__ apeP,
    const int* __restrict__ cnt, float* __restrict__ out)
{
  __shared__ float psum[8][32];
  const int b = blockIdx.x;
  const int jg = blockIdx.y;
  const int t = threadIdx.x;
  const int col = jg*32 + (t & 31);
  const int rseg = t >> 5;
  const float* base = apeP + ((size_t)b*512)*1024 + col;
  float acc = 0.f;
  #pragma unroll 8
  for (int i = 0; i < 64; ++i)
    acc += base[(size_t)(rseg + 8*i) << 10];
  psum[rseg][t & 31] = acc;
  __syncthreads();
  if (t < 32){
    float sv = 0.f;
    #pragma unroll
    for (int r2 = 0; r2 < 8; ++r2) sv += psum[r2][t];
    const int j = jg*32 + t;
    const int c = cnt[b*NB_E + j];
    out[b*NB_E + j] = c > 0 ? sv / (float)c : 0.f;
  }
}

extern "C" void kernel_launch(void* const* d_in, const int* in_sizes, int n_in,
                              void* d_out, int out_size, void* d_ws, size_t ws_size,
                              hipStream_t stream)
{
  const float* x        = (const float*)d_in[0];
  const int*   dist     = (const int*)d_in[1];
  const float* base_rpr = (const float*)d_in[2];
  const float* w_q      = (const float*)d_in[3];
  const float* w_k      = (const float*)d_in[4];
  const float* w_v      = (const float*)d_in[5];
  const float* w_fc     = (const float*)d_in[6];
  const float* ln_g     = (const float*)d_in[7];
  const float* ln_b     = (const float*)d_in[8];

  float* x_out    = (float*)d_out;
  float* attn_out = x_out + (size_t)NB_B*NB_DM*NB_E;
  float* ape_out  = attn_out + (size_t)NB_B*NB_H*NB_E*NB_E;

  unsigned char* ws = (unsigned char*)d_ws;
  unsigned short* s_bf   = (unsigned short*)(ws);             // [0, 2MB)
  unsigned short* qn_bf  = (unsigned short*)(ws + 2097152);   // [2MB, 4MB)
  float*          apeP   = (float*)(ws);                      // overlays [0,4MB) after QKV
  unsigned short* wT     = (unsigned short*)(ws + 4194304);   // 4 x 512x512 bf16
  unsigned short* Qb     = (unsigned short*)(ws + 6291456);
  unsigned short* Kb     = (unsigned short*)(ws + 8388608);
  unsigned short* VTb    = (unsigned short*)(ws + 10485760);
  unsigned short* outb   = (unsigned short*)(ws + 12582912);
  float*          qr     = (float*)(ws + 14680064);           // 512KB
  unsigned char*  d8     = ws + 15204352;                     // 2MB
  int*            cnt    = (int*)(ws + 17301504);             // 8KB
  float*          kscr   = (float*)(ws + 17317888);           // ~496KB ablation scratch
  const size_t    PG_OFF = 17825792;                          // 32MB region
  unsigned short* Pg     = (unsigned short*)(ws + PG_OFF);
  const bool big_ws = ws_size >= PG_OFF + (size_t)33554432;

  (void)hipMemsetAsync(cnt, 0, 8192, stream);

  k_transpose_w<<<dim3(16,16,4), dim3(32,8), 0, stream>>>(w_q, w_k, w_v, w_fc, wT);
  k_transpose_x<<<dim3(32,16,2), dim3(32,8), 0, stream>>>(x, s_bf);
  k_ln<<<dim3(512), dim3(256), 0, stream>>>(s_bf, qn_bf, ln_g, ln_b);
  k_dist<<<dim3(64,2), dim3(256), 0, stream>>>(dist, d8, cnt);

  k_gemm_qkv<<<dim3(32,8,3), dim3(256), 0, stream>>>(qn_bf, s_bf, wT, base_rpr,
                                                     Qb, Kb, VTb, qr);

  if (big_ws){
    k_attn<4,true><<<dim3(1024), dim3(512), 0, stream>>>(Qb, Kb, VTb, qr, d8,
                                                 attn_out, Pg, outb, apeP, kscr);
    k_expand<<<dim3(128,16), dim3(256), 0, stream>>>(Pg, attn_out);
    // ---- ablation probes (scratch-only writes; rocprof per-dispatch rows) ----
    k_attn<1,true><<<dim3(1024), dim3(512), 0, stream>>>(Qb, Kb, VTb, qr, d8,
                                                 attn_out, Pg, outb, apeP, kscr);
    k_attn<2,true><<<dim3(1024), dim3(512), 0, stream>>>(Qb, Kb, VTb, qr, d8,
                                                 attn_out, Pg, outb, apeP, kscr);
    k_attn<3,true><<<dim3(1024), dim3(512), 0, stream>>>(Qb, Kb, VTb, qr, d8,
                                                 attn_out, Pg, outb, apeP, kscr);
  } else {
    k_attn<4,false><<<dim3(1024), dim3(512), 0, stream>>>(Qb, Kb, VTb, qr, d8,
                                                 attn_out, Pg, outb, apeP, kscr);
  }

  k_fc<<<dim3(32,16), dim3(256), 0, stream>>>(outb, wT + 786432, x_out, x);
  k_apered<<<dim3(2,32), dim3(256), 0, stream>>>(apeP, cnt, ape_out);
}

// Round 9
// 149.486 us; speedup vs baseline: 1.3627x; 1.3627x over previous
//
#include <hip/hip_runtime.h>

#define NB_B 2
#define NB_E 1024
#define NB_DM 512
#define NB_H 8

typedef __attribute__((ext_vector_type(8))) __bf16 bf16x8;
typedef __attribute__((ext_vector_type(8))) unsigned short u16x8;
typedef __attribute__((ext_vector_type(4))) float f32x4;

static __device__ __forceinline__ float bf2f(unsigned short u){
  union { unsigned int i; float f; } v; v.i = ((unsigned int)u) << 16; return v.f;
}
static __device__ __forceinline__ unsigned short f2bf(float f){
  union { float f; unsigned int i; } v; v.f = f;
  unsigned int r = v.i + 0x7FFFu + ((v.i >> 16) & 1u);
  return (unsigned short)(r >> 16);
}
static __device__ __forceinline__ f32x4 mfma16(bf16x8 a, bf16x8 b, f32x4 c){
  return __builtin_amdgcn_mfma_f32_16x16x32_bf16(a, b, c, 0, 0, 0);
}
static __device__ __forceinline__ float fast_exp2(float x){
#if __has_builtin(__builtin_amdgcn_exp2f)
  return __builtin_amdgcn_exp2f(x);
#else
  return exp2f(x);
#endif
}

// ---- transpose x [B,DM,E] (f32) -> s_bf [B,E,DM] (bf16) ----
__global__ void k_transpose_x(const float* __restrict__ x, unsigned short* __restrict__ s_bf){
  __shared__ float tile[32][33];
  const int b = blockIdx.z;
  const int d0 = blockIdx.y * 32;
  const int e0 = blockIdx.x * 32;
  const int tx = threadIdx.x, ty = threadIdx.y;
  #pragma unroll
  for (int r = 0; r < 4; ++r){
    const int d = d0 + ty + r*8;
    tile[ty + r*8][tx] = x[((size_t)b*NB_DM + d)*NB_E + e0 + tx];
  }
  __syncthreads();
  #pragma unroll
  for (int r = 0; r < 4; ++r){
    const int e = e0 + ty + r*8;
    s_bf[((size_t)b*NB_E + e)*NB_DM + d0 + tx] = f2bf(tile[tx][ty + r*8]);
  }
}

// ---- transpose 4 weights [512,512] f32 -> wT bf16 [which][n][k] ----
__global__ void k_transpose_w(const float* __restrict__ w0, const float* __restrict__ w1,
                              const float* __restrict__ w2, const float* __restrict__ w3,
                              unsigned short* __restrict__ wT){
  __shared__ float tile[32][33];
  const int which = blockIdx.z;
  const float* w = which==0 ? w0 : which==1 ? w1 : which==2 ? w2 : w3;
  unsigned short* dst = wT + (size_t)which*512*512;
  const int k0 = blockIdx.y*32, n0 = blockIdx.x*32;
  const int tx = threadIdx.x, ty = threadIdx.y;
  #pragma unroll
  for (int r = 0; r < 4; ++r)
    tile[ty + r*8][tx] = w[(size_t)(k0 + ty + r*8)*512 + n0 + tx];
  __syncthreads();
  #pragma unroll
  for (int r = 0; r < 4; ++r)
    dst[(size_t)(n0 + ty + r*8)*512 + k0 + tx] = f2bf(tile[tx][ty + r*8]);
}

// ---- layernorm rows of s_bf -> qn_bf (4 rows per 256-thread block) ----
__global__ __launch_bounds__(256) void k_ln(const unsigned short* __restrict__ s_bf,
    unsigned short* __restrict__ qn_bf, const float* __restrict__ gg, const float* __restrict__ bb){
  const int row = blockIdx.x*4 + (threadIdx.x >> 6);
  const int l = threadIdx.x & 63;
  const unsigned short* sp = s_bf + (size_t)row*512 + l*8;
  u16x8 v = *(const u16x8*)sp;
  float f[8]; float sum = 0.f, sq = 0.f;
  #pragma unroll
  for (int i = 0; i < 8; ++i){ f[i] = bf2f(v[i]); sum += f[i]; sq += f[i]*f[i]; }
  #pragma unroll
  for (int off = 32; off >= 1; off >>= 1){
    sum += __shfl_xor(sum, off);
    sq  += __shfl_xor(sq, off);
  }
  const float mu  = sum * (1.f/512.f);
  const float var = sq * (1.f/512.f) - mu*mu;
  const float rstd = rsqrtf(var + 1e-6f);
  const float4 g0 = *(const float4*)(gg + l*8);
  const float4 g1 = *(const float4*)(gg + l*8 + 4);
  const float4 b0 = *(const float4*)(bb + l*8);
  const float4 b1 = *(const float4*)(bb + l*8 + 4);
  const float gv[8] = {g0.x,g0.y,g0.z,g0.w,g1.x,g1.y,g1.z,g1.w};
  const float bv[8] = {b0.x,b0.y,b0.z,b0.w,b1.x,b1.y,b1.z,b1.w};
  u16x8 o;
  #pragma unroll
  for (int i = 0; i < 8; ++i) o[i] = f2bf((f[i]-mu)*rstd*gv[i] + bv[i]);
  *(u16x8*)(qn_bf + (size_t)row*512 + l*8) = o;
}

// ---- classify dist -> uint8 (0..5 = rpr class, 6 = masked) + column counts ----
__global__ __launch_bounds__(256) void k_dist(const int* __restrict__ dist,
    unsigned char* __restrict__ d8, int* __restrict__ cnt){
  const int b = blockIdx.y;
  const int i0 = blockIdx.x * 16;
  const int t = threadIdx.x;
  int c0 = 0, c1 = 0, c2 = 0, c3 = 0;
  #pragma unroll 4
  for (int r = 0; r < 16; ++r){
    const int row = i0 + r;
    const int4 d = ((const int4*)(dist + ((size_t)b*NB_E + row)*NB_E))[t];
    uchar4 o;
    o.x = (unsigned char)(d.x <= 5 ? d.x : 6);
    o.y = (unsigned char)(d.y <= 5 ? d.y : 6);
    o.z = (unsigned char)(d.z <= 5 ? d.z : 6);
    o.w = (unsigned char)(d.w <= 5 ? d.w : 6);
    ((uchar4*)(d8 + ((size_t)b*NB_E + row)*NB_E))[t] = o;
    c0 += (d.x <= 5); c1 += (d.y <= 5); c2 += (d.z <= 5); c3 += (d.w <= 5);
  }
  int* cb = cnt + b*NB_E + t*4;
  atomicAdd(cb + 0, c0);
  atomicAdd(cb + 1, c1);
  atomicAdd(cb + 2, c2);
  atomicAdd(cb + 3, c3);
}

// ---- fused QKV GEMM: z=0 -> Q (scaled 1/8, + qr table), z=1 -> K, z=2 -> V^T ----
__global__ __launch_bounds__(256, 4) void k_gemm_qkv(
    const unsigned short* __restrict__ qn, const unsigned short* __restrict__ s,
    const unsigned short* __restrict__ wT, const float* __restrict__ base_rpr,
    unsigned short* __restrict__ Qb, unsigned short* __restrict__ Kb,
    unsigned short* __restrict__ VTb, float* __restrict__ qr)
{
  const int z = blockIdx.z;
  const unsigned short* A  = (z == 0) ? qn : s;
  const unsigned short* BT = wT + (size_t)z*262144;
  const int tid = threadIdx.x;
  const int l = tid & 63, wv = tid >> 6;
  const int ll = l & 15, lg = l >> 4;
  const int m0 = blockIdx.x*64 + wv*16;
  const int n0 = blockIdx.y*64;
  const unsigned short* arow = A + (size_t)(m0 + ll)*512 + lg*8;
  const unsigned short* brow = BT + (size_t)(n0 + ll)*512 + lg*8;
  f32x4 acc[4];
  #pragma unroll
  for (int nt = 0; nt < 4; ++nt) acc[nt] = (f32x4){0.f,0.f,0.f,0.f};
  bf16x8 a_c = *(const bf16x8*)(arow);
  bf16x8 b_c[4];
  #pragma unroll
  for (int nt = 0; nt < 4; ++nt) b_c[nt] = *(const bf16x8*)(brow + (size_t)nt*8192);
  #pragma unroll
  for (int ks = 0; ks < 16; ++ks){
    const int kn = (ks + 1) & 15;
    bf16x8 a_n = *(const bf16x8*)(arow + kn*32);
    bf16x8 b_n[4];
    #pragma unroll
    for (int nt = 0; nt < 4; ++nt) b_n[nt] = *(const bf16x8*)(brow + (size_t)nt*8192 + kn*32);
    #pragma unroll
    for (int nt = 0; nt < 4; ++nt) acc[nt] = mfma16(a_c, b_c[nt], acc[nt]);
    a_c = a_n;
    #pragma unroll
    for (int nt = 0; nt < 4; ++nt) b_c[nt] = b_n[nt];
  }
  const int rbase = m0 + lg*4;
  const int bidx = rbase >> 10;
  const int e = rbase & 1023;
  const int h = n0 >> 6;
  if (z == 0){
    float rprv[6][4];
    #pragma unroll
    for (int c = 0; c < 6; ++c)
      #pragma unroll
      for (int nt = 0; nt < 4; ++nt)
        rprv[c][nt] = base_rpr[c*64 + nt*16 + ll];
    #pragma unroll
    for (int nt = 0; nt < 4; ++nt){
      const int dk = nt*16 + ll;
      unsigned short* dp = Qb + (((size_t)bidx*NB_H + h)*NB_E + e)*64 + dk;
      #pragma unroll
      for (int r = 0; r < 4; ++r)
        dp[(size_t)r*64] = f2bf(acc[nt][r]*0.125f);
    }
    #pragma unroll
    for (int r = 0; r < 4; ++r){
      #pragma unroll
      for (int c = 0; c < 6; ++c){
        float tv = 0.f;
        #pragma unroll
        for (int nt = 0; nt < 4; ++nt) tv += acc[nt][r]*0.125f*rprv[c][nt];
        tv += __shfl_xor(tv, 1);
        tv += __shfl_xor(tv, 2);
        tv += __shfl_xor(tv, 4);
        tv += __shfl_xor(tv, 8);
        if (ll == 0)
          qr[(((size_t)(bidx*NB_H + h)*NB_E) + e + r)*8 + c] = tv;
      }
    }
  } else if (z == 1){
    #pragma unroll
    for (int nt = 0; nt < 4; ++nt){
      const int dk = nt*16 + ll;
      unsigned short* dp = Kb + (((size_t)bidx*NB_H + h)*NB_E + e)*64 + dk;
      #pragma unroll
      for (int r = 0; r < 4; ++r)
        dp[(size_t)r*64] = f2bf(acc[nt][r]);
    }
  } else {
    #pragma unroll
    for (int nt = 0; nt < 4; ++nt){
      const int dv = nt*16 + ll;
      ushort4 ov;
      ov.x = f2bf(acc[nt][0]); ov.y = f2bf(acc[nt][1]);
      ov.z = f2bf(acc[nt][2]); ov.w = f2bf(acc[nt][3]);
      *(ushort4*)(VTb + (((size_t)bidx*NB_H + h)*64 + dv)*NB_E + e) = ov;
    }
  }
}

// ---- FC GEMM: x_out f32 [B,DM,E] = outb @ w_fc^T + residual; 16x32 wave tiles ----
__global__ __launch_bounds__(256, 4) void k_fc(
    const unsigned short* __restrict__ A, const unsigned short* __restrict__ BT,
    float* __restrict__ dst_f, const float* __restrict__ resid)
{
  const int tid = threadIdx.x;
  const int l = tid & 63, wv = tid >> 6;
  const int ll = l & 15, lg = l >> 4;
  const int m0 = blockIdx.x*64 + wv*16;
  const int n0 = blockIdx.y*32;
  const unsigned short* arow = A + (size_t)(m0 + ll)*512 + lg*8;
  const unsigned short* brow = BT + (size_t)(n0 + ll)*512 + lg*8;
  f32x4 acc[2];
  acc[0] = (f32x4){0.f,0.f,0.f,0.f};
  acc[1] = (f32x4){0.f,0.f,0.f,0.f};
  bf16x8 a_c = *(const bf16x8*)(arow);
  bf16x8 b_c0 = *(const bf16x8*)(brow);
  bf16x8 b_c1 = *(const bf16x8*)(brow + 8192);
  #pragma unroll
  for (int ks = 0; ks < 16; ++ks){
    const int kn = (ks + 1) & 15;
    bf16x8 a_n  = *(const bf16x8*)(arow + kn*32);
    bf16x8 b_n0 = *(const bf16x8*)(brow + kn*32);
    bf16x8 b_n1 = *(const bf16x8*)(brow + 8192 + kn*32);
    acc[0] = mfma16(a_c, b_c0, acc[0]);
    acc[1] = mfma16(a_c, b_c1, acc[1]);
    a_c = a_n; b_c0 = b_n0; b_c1 = b_n1;
  }
  const int rbase = m0 + lg*4;
  const int bidx = rbase >> 10;
  const int e = rbase & 1023;
  #pragma unroll
  for (int nt = 0; nt < 2; ++nt){
    const int n = n0 + nt*16 + ll;
    const float* xr = resid + ((size_t)bidx*NB_DM + n)*NB_E + e;
    const float4 rv = *(const float4*)xr;
    const float4 ov = make_float4(acc[nt][0]+rv.x, acc[nt][1]+rv.y,
                                  acc[nt][2]+rv.z, acc[nt][3]+rv.w);
    *(float4*)(dst_f + ((size_t)bidx*NB_DM + n)*NB_E + e) = ov;
  }
}

// ---- fused attention: 2048 blocks x 512 threads (8 waves), 8 q-rows per block.
// Wave w owns j in [w*128, w*128+128). No-max softmax (logits bounded; masked -> 0).
// MFMA rows 8-15 are duplicates of 0-7 (row = ll&7); only il<8 results are used.
// LDS: qr_l [0,192) | reds [256,512) | d8 [1024,9216) | P bf16 [10240,26624) swizzled
#define D_OFF 1024
#define P_OFF 10240
__global__ __launch_bounds__(512, 8) void k_attn(
    const unsigned short* __restrict__ Q, const unsigned short* __restrict__ K,
    const unsigned short* __restrict__ VT, const float* __restrict__ qr,
    const unsigned char* __restrict__ d8, float* __restrict__ attn_out,
    unsigned short* __restrict__ outb, float* __restrict__ apeacc16)
{
  __shared__ __align__(16) unsigned char smem[26624];
  unsigned short* plds = (unsigned short*)(smem + P_OFF);
  float* qr_l = (float*)smem;                 // 48 f
  float* reds = (float*)(smem + 256);         // 8 waves x 8 rows

  const int tid = threadIdx.x;
  const int l = tid & 63, w = tid >> 6;       // 8 waves
  const int lg = l >> 4, ll = l & 15;
  const int n = blockIdx.x;
  const int m = n >> 3;                       // 0..255
  const int bh = (n & 7)*2 + (m >> 7);        // b*H + h  (XCD-locality decode)
  const int b = bh >> 3;
  const int ib = (m & 127) << 3;              // 8-row tile
  const int j0 = w << 7;                      // 128 cols per wave

  // d8 tile (8 rows x 1024 = 8KB) -> LDS
  const unsigned char* d8g = d8 + ((size_t)b*NB_E + ib)*NB_E;
  const int4 dr0 = ((const int4*)d8g)[tid];
  ((int4*)(smem + D_OFF))[tid] = dr0;

  if (tid < 48)
    qr_l[tid] = qr[((size_t)bh*NB_E + ib + (tid/6))*8 + (tid % 6)];

  const unsigned short* Qbp = Q + ((size_t)bh*NB_E + ib)*64;
  bf16x8 qf0 = *(const bf16x8*)(Qbp + (size_t)(ll & 7)*64 + lg*8);
  bf16x8 qf1 = *(const bf16x8*)(Qbp + (size_t)(ll & 7)*64 + 32 + lg*8);

  // S = (Q/8) K^T over this wave's 128 cols
  f32x4 s[8];
  const unsigned short* Kb = K + (size_t)bh*NB_E*64;
  #pragma unroll
  for (int jt = 0; jt < 8; ++jt){
    const size_t krow = (size_t)(j0 + jt*16 + ll)*64;
    bf16x8 k0 = *(const bf16x8*)(Kb + krow + lg*8);
    bf16x8 k1 = *(const bf16x8*)(Kb + krow + 32 + lg*8);
    f32x4 acc = {0.f,0.f,0.f,0.f};
    acc = mfma16(qf0, k0, acc);
    acc = mfma16(qf1, k1, acc);
    s[jt] = acc;
  }
  __syncthreads();

  // bias + exp + row-sum (rows il<8 live in lanes lg<2)
  if (lg < 2){
    float rsum[4] = {0.f, 0.f, 0.f, 0.f};
    #pragma unroll
    for (int jt = 0; jt < 8; ++jt){
      const int j = j0 + jt*16 + ll;
      #pragma unroll
      for (int r = 0; r < 4; ++r){
        const int il = lg*4 + r;
        const unsigned char c = smem[D_OFF + il*1024 + j];
        const float p = (c < 6)
          ? fast_exp2((s[jt][r] + qr_l[il*6 + c]) * 1.4426950408889634f) : 0.f;
        s[jt][r] = p;
        rsum[r] += p;
      }
    }
    #pragma unroll
    for (int r = 0; r < 4; ++r){
      float sum = rsum[r];
      sum += __shfl_xor(sum, 1);
      sum += __shfl_xor(sum, 2);
      sum += __shfl_xor(sum, 4);
      sum += __shfl_xor(sum, 8);
      if (ll == 0) reds[w*8 + lg*4 + r] = sum;
    }
  }
  __syncthreads();

  if (lg < 2){
    float rinv[4];
    #pragma unroll
    for (int r = 0; r < 4; ++r){
      const int il = lg*4 + r;
      float tot = 0.f;
      #pragma unroll
      for (int wv = 0; wv < 8; ++wv) tot += reds[wv*8 + il];
      rinv[r] = 1.0f / (tot + 1e-30f);
    }
    // normalize: P -> bf16 LDS (XOR-swizzled) + ape column sums (atomic, low contention)
    #pragma unroll
    for (int jt = 0; jt < 8; ++jt){
      const int j = j0 + jt*16 + ll;
      float csum = 0.f;
      #pragma unroll
      for (int r = 0; r < 4; ++r){
        const int il = lg*4 + r;
        const float pn = s[jt][r] * rinv[r];
        const int byo = ((il*1024 + j)*2) ^ (il << 4);
        plds[byo >> 1] = f2bf(pn);
        csum += pn;
      }
      csum += __shfl_xor(csum, 16);          // lg0 <-> lg1
      if (lg == 0) atomicAdd(&apeacc16[(bh << 10) + j], csum);
    }
  }
  __syncthreads();

  if (w < 4){
    // PV: wave w -> dv chunk [w*16, w*16+16); P rows duplicated (ll&7)
    const unsigned short* Vb = VT + ((size_t)bh*64 + w*16 + ll)*NB_E;
    f32x4 o = {0.f,0.f,0.f,0.f};
    #pragma unroll 4
    for (int kk = 0; kk < 32; ++kk){
      bf16x8 vf = *(const bf16x8*)(Vb + kk*32 + lg*8);
      const int byo = (((ll & 7)*1024 + kk*32 + lg*8)*2) ^ ((ll & 7) << 4);
      bf16x8 p = *(const bf16x8*)(smem + P_OFF + byo);
      o = mfma16(p, vf, o);
    }
    if (lg < 2){
      const int coln = (bh & 7)*64 + w*16 + ll;
      #pragma unroll
      for (int r = 0; r < 4; ++r){
        const int e0 = ib + lg*4 + r;
        outb[((size_t)b*NB_E + e0)*512 + coln] = f2bf(o[r]);
      }
    }
  }

  // attn store: each wave stores row w (full-line f32x4, 1KB per instruction)
  {
    float* arow = attn_out + ((size_t)bh*NB_E + ib + w)*NB_E;
    #pragma unroll
    for (int c2 = 0; c2 < 4; ++c2){
      const int col = c2*256 + l*4;
      const int byo = ((w*1024 + col)*2) ^ (w << 4);
      const ushort4 pv = *(const ushort4*)(smem + P_OFF + byo);
      f32x4 ov;
      ov[0] = bf2f(pv.x); ov[1] = bf2f(pv.y); ov[2] = bf2f(pv.z); ov[3] = bf2f(pv.w);
      *(f32x4*)(arow + col) = ov;
    }
  }
}

// ---- attn_per_edge finalize: sum 8 heads, divide by count ----
__global__ void k_ape(const float* __restrict__ acc, const int* __restrict__ cnt,
                      float* __restrict__ out){
  const int t = blockIdx.x*256 + threadIdx.x;
  if (t < NB_B*NB_E){
    const int b = t >> 10, j = t & 1023;
    float ssum = 0.f;
    #pragma unroll
    for (int h = 0; h < 8; ++h) ssum += acc[(((b<<3) + h) << 10) + j];
    const int c = cnt[t];
    out[t] = c > 0 ? ssum / (float)c : 0.f;
  }
}

extern "C" void kernel_launch(void* const* d_in, const int* in_sizes, int n_in,
                              void* d_out, int out_size, void* d_ws, size_t ws_size,
                              hipStream_t stream)
{
  const float* x        = (const float*)d_in[0];
  const int*   dist     = (const int*)d_in[1];
  const float* base_rpr = (const float*)d_in[2];
  const float* w_q      = (const float*)d_in[3];
  const float* w_k      = (const float*)d_in[4];
  const float* w_v      = (const float*)d_in[5];
  const float* w_fc     = (const float*)d_in[6];
  const float* ln_g     = (const float*)d_in[7];
  const float* ln_b     = (const float*)d_in[8];

  float* x_out    = (float*)d_out;
  float* attn_out = x_out + (size_t)NB_B*NB_DM*NB_E;
  float* ape_out  = attn_out + (size_t)NB_B*NB_H*NB_E*NB_E;

  unsigned char* ws = (unsigned char*)d_ws;
  unsigned short* s_bf   = (unsigned short*)(ws);             // [0, 2MB)
  unsigned short* qn_bf  = (unsigned short*)(ws + 2097152);   // [2MB, 4MB)
  unsigned short* wT     = (unsigned short*)(ws + 4194304);   // 4 x 512x512 bf16
  unsigned short* Qb     = (unsigned short*)(ws + 6291456);
  unsigned short* Kb     = (unsigned short*)(ws + 8388608);
  unsigned short* VTb    = (unsigned short*)(ws + 10485760);
  unsigned short* outb   = (unsigned short*)(ws + 12582912);
  float*          qr     = (float*)(ws + 14680064);           // 512KB
  unsigned char*  d8     = ws + 15204352;                     // 2MB
  int*            cnt    = (int*)(ws + 17301504);             // 8KB
  float*          ape16  = (float*)(ws + 17309696);           // 64KB per-head accumulators

  (void)hipMemsetAsync(cnt, 0, 8192 + 65536, stream);         // cnt + ape16

  k_transpose_w<<<dim3(16,16,4), dim3(32,8), 0, stream>>>(w_q, w_k, w_v, w_fc, wT);
  k_transpose_x<<<dim3(32,16,2), dim3(32,8), 0, stream>>>(x, s_bf);
  k_ln<<<dim3(512), dim3(256), 0, stream>>>(s_bf, qn_bf, ln_g, ln_b);
  k_dist<<<dim3(64,2), dim3(256), 0, stream>>>(dist, d8, cnt);

  k_gemm_qkv<<<dim3(32,8,3), dim3(256), 0, stream>>>(qn_bf, s_bf, wT, base_rpr,
                                                     Qb, Kb, VTb, qr);

  k_attn<<<dim3(2048), dim3(512), 0, stream>>>(Qb, Kb, VTb, qr, d8,
                                               attn_out, outb, ape16);

  k_fc<<<dim3(32,16), dim3(256), 0, stream>>>(outb, wT + 786432, x_out, x);
  k_ape<<<dim3(8), dim3(256), 0, stream>>>(ape16, cnt, ape_out);
}

// Round 10
// 128.826 us; speedup vs baseline: 1.5812x; 1.1604x over previous
//
#include <hip/hip_runtime.h>

#define NB_B 2
#define NB_E 1024
#define NB_DM 512
#define NB_H 8

typedef __attribute__((ext_vector_type(8))) __bf16 bf16x8;
typedef __attribute__((ext_vector_type(8))) unsigned short u16x8;
typedef __attribute__((ext_vector_type(4))) float f32x4;

static __device__ __forceinline__ float bf2f(unsigned short u){
  union { unsigned int i; float f; } v; v.i = ((unsigned int)u) << 16; return v.f;
}
static __device__ __forceinline__ unsigned short f2bf(float f){
  union { float f; unsigned int i; } v; v.f = f;
  unsigned int r = v.i + 0x7FFFu + ((v.i >> 16) & 1u);
  return (unsigned short)(r >> 16);
}
static __device__ __forceinline__ f32x4 mfma16(bf16x8 a, bf16x8 b, f32x4 c){
  return __builtin_amdgcn_mfma_f32_16x16x32_bf16(a, b, c, 0, 0, 0);
}
static __device__ __forceinline__ float fast_exp2(float x){
#if __has_builtin(__builtin_amdgcn_exp2f)
  return __builtin_amdgcn_exp2f(x);
#else
  return exp2f(x);
#endif
}

// ---- zero cnt (device-scope; replaces hipMemsetAsync to avoid system-scope drain) ----
__global__ __launch_bounds__(512) void k_zero(int* __restrict__ cnt){
  ((int4*)cnt)[threadIdx.x] = make_int4(0,0,0,0);
}

// ---- transpose x [B,DM,E] (f32) -> s_bf [B,E,DM] (bf16) ----
__global__ void k_transpose_x(const float* __restrict__ x, unsigned short* __restrict__ s_bf){
  __shared__ float tile[32][33];
  const int b = blockIdx.z;
  const int d0 = blockIdx.y * 32;
  const int e0 = blockIdx.x * 32;
  const int tx = threadIdx.x, ty = threadIdx.y;
  #pragma unroll
  for (int r = 0; r < 4; ++r){
    const int d = d0 + ty + r*8;
    tile[ty + r*8][tx] = x[((size_t)b*NB_DM + d)*NB_E + e0 + tx];
  }
  __syncthreads();
  #pragma unroll
  for (int r = 0; r < 4; ++r){
    const int e = e0 + ty + r*8;
    s_bf[((size_t)b*NB_E + e)*NB_DM + d0 + tx] = f2bf(tile[tx][ty + r*8]);
  }
}

// ---- transpose 4 weights [512,512] f32 -> wT bf16 [which][n][k] ----
__global__ void k_transpose_w(const float* __restrict__ w0, const float* __restrict__ w1,
                              const float* __restrict__ w2, const float* __restrict__ w3,
                              unsigned short* __restrict__ wT){
  __shared__ float tile[32][33];
  const int which = blockIdx.z;
  const float* w = which==0 ? w0 : which==1 ? w1 : which==2 ? w2 : w3;
  unsigned short* dst = wT + (size_t)which*512*512;
  const int k0 = blockIdx.y*32, n0 = blockIdx.x*32;
  const int tx = threadIdx.x, ty = threadIdx.y;
  #pragma unroll
  for (int r = 0; r < 4; ++r)
    tile[ty + r*8][tx] = w[(size_t)(k0 + ty + r*8)*512 + n0 + tx];
  __syncthreads();
  #pragma unroll
  for (int r = 0; r < 4; ++r)
    dst[(size_t)(n0 + ty + r*8)*512 + k0 + tx] = f2bf(tile[tx][ty + r*8]);
}

// ---- layernorm rows of s_bf -> qn_bf (4 rows per 256-thread block) ----
__global__ __launch_bounds__(256) void k_ln(const unsigned short* __restrict__ s_bf,
    unsigned short* __restrict__ qn_bf, const float* __restrict__ gg, const float* __restrict__ bb){
  const int row = blockIdx.x*4 + (threadIdx.x >> 6);
  const int l = threadIdx.x & 63;
  const unsigned short* sp = s_bf + (size_t)row*512 + l*8;
  u16x8 v = *(const u16x8*)sp;
  float f[8]; float sum = 0.f, sq = 0.f;
  #pragma unroll
  for (int i = 0; i < 8; ++i){ f[i] = bf2f(v[i]); sum += f[i]; sq += f[i]*f[i]; }
  #pragma unroll
  for (int off = 32; off >= 1; off >>= 1){
    sum += __shfl_xor(sum, off);
    sq  += __shfl_xor(sq, off);
  }
  const float mu  = sum * (1.f/512.f);
  const float var = sq * (1.f/512.f) - mu*mu;
  const float rstd = rsqrtf(var + 1e-6f);
  const float4 g0 = *(const float4*)(gg + l*8);
  const float4 g1 = *(const float4*)(gg + l*8 + 4);
  const float4 b0 = *(const float4*)(bb + l*8);
  const float4 b1 = *(const float4*)(bb + l*8 + 4);
  const float gv[8] = {g0.x,g0.y,g0.z,g0.w,g1.x,g1.y,g1.z,g1.w};
  const float bv[8] = {b0.x,b0.y,b0.z,b0.w,b1.x,b1.y,b1.z,b1.w};
  u16x8 o;
  #pragma unroll
  for (int i = 0; i < 8; ++i) o[i] = f2bf((f[i]-mu)*rstd*gv[i] + bv[i]);
  *(u16x8*)(qn_bf + (size_t)row*512 + l*8) = o;
}

// ---- classify dist -> uint8 (0..5 = rpr class, 6 = masked) + column counts ----
__global__ __launch_bounds__(256) void k_dist(const int* __restrict__ dist,
    unsigned char* __restrict__ d8, int* __restrict__ cnt){
  const int b = blockIdx.y;
  const int i0 = blockIdx.x * 16;
  const int t = threadIdx.x;
  int c0 = 0, c1 = 0, c2 = 0, c3 = 0;
  #pragma unroll 4
  for (int r = 0; r < 16; ++r){
    const int row = i0 + r;
    const int4 d = ((const int4*)(dist + ((size_t)b*NB_E + row)*NB_E))[t];
    uchar4 o;
    o.x = (unsigned char)(d.x <= 5 ? d.x : 6);
    o.y = (unsigned char)(d.y <= 5 ? d.y : 6);
    o.z = (unsigned char)(d.z <= 5 ? d.z : 6);
    o.w = (unsigned char)(d.w <= 5 ? d.w : 6);
    ((uchar4*)(d8 + ((size_t)b*NB_E + row)*NB_E))[t] = o;
    c0 += (d.x <= 5); c1 += (d.y <= 5); c2 += (d.z <= 5); c3 += (d.w <= 5);
  }
  int* cb = cnt + b*NB_E + t*4;
  atomicAdd(cb + 0, c0);
  atomicAdd(cb + 1, c1);
  atomicAdd(cb + 2, c2);
  atomicAdd(cb + 3, c3);
}

// ---- fused QKV GEMM: z=0 -> Q (scaled 1/8, + qr table), z=1 -> K, z=2 -> V^T ----
__global__ __launch_bounds__(256, 4) void k_gemm_qkv(
    const unsigned short* __restrict__ qn, const unsigned short* __restrict__ s,
    const unsigned short* __restrict__ wT, const float* __restrict__ base_rpr,
    unsigned short* __restrict__ Qb, unsigned short* __restrict__ Kb,
    unsigned short* __restrict__ VTb, float* __restrict__ qr)
{
  const int z = blockIdx.z;
  const unsigned short* A  = (z == 0) ? qn : s;
  const unsigned short* BT = wT + (size_t)z*262144;
  const int tid = threadIdx.x;
  const int l = tid & 63, wv = tid >> 6;
  const int ll = l & 15, lg = l >> 4;
  const int m0 = blockIdx.x*64 + wv*16;
  const int n0 = blockIdx.y*64;
  const unsigned short* arow = A + (size_t)(m0 + ll)*512 + lg*8;
  const unsigned short* brow = BT + (size_t)(n0 + ll)*512 + lg*8;
  f32x4 acc[4];
  #pragma unroll
  for (int nt = 0; nt < 4; ++nt) acc[nt] = (f32x4){0.f,0.f,0.f,0.f};
  bf16x8 a_c = *(const bf16x8*)(arow);
  bf16x8 b_c[4];
  #pragma unroll
  for (int nt = 0; nt < 4; ++nt) b_c[nt] = *(const bf16x8*)(brow + (size_t)nt*8192);
  #pragma unroll
  for (int ks = 0; ks < 16; ++ks){
    const int kn = (ks + 1) & 15;
    bf16x8 a_n = *(const bf16x8*)(arow + kn*32);
    bf16x8 b_n[4];
    #pragma unroll
    for (int nt = 0; nt < 4; ++nt) b_n[nt] = *(const bf16x8*)(brow + (size_t)nt*8192 + kn*32);
    #pragma unroll
    for (int nt = 0; nt < 4; ++nt) acc[nt] = mfma16(a_c, b_c[nt], acc[nt]);
    a_c = a_n;
    #pragma unroll
    for (int nt = 0; nt < 4; ++nt) b_c[nt] = b_n[nt];
  }
  const int rbase = m0 + lg*4;
  const int bidx = rbase >> 10;
  const int e = rbase & 1023;
  const int h = n0 >> 6;
  if (z == 0){
    float rprv[6][4];
    #pragma unroll
    for (int c = 0; c < 6; ++c)
      #pragma unroll
      for (int nt = 0; nt < 4; ++nt)
        rprv[c][nt] = base_rpr[c*64 + nt*16 + ll];
    #pragma unroll
    for (int nt = 0; nt < 4; ++nt){
      const int dk = nt*16 + ll;
      unsigned short* dp = Qb + (((size_t)bidx*NB_H + h)*NB_E + e)*64 + dk;
      #pragma unroll
      for (int r = 0; r < 4; ++r)
        dp[(size_t)r*64] = f2bf(acc[nt][r]*0.125f);
    }
    #pragma unroll
    for (int r = 0; r < 4; ++r){
      #pragma unroll
      for (int c = 0; c < 6; ++c){
        float tv = 0.f;
        #pragma unroll
        for (int nt = 0; nt < 4; ++nt) tv += acc[nt][r]*0.125f*rprv[c][nt];
        tv += __shfl_xor(tv, 1);
        tv += __shfl_xor(tv, 2);
        tv += __shfl_xor(tv, 4);
        tv += __shfl_xor(tv, 8);
        if (ll == 0)
          qr[(((size_t)(bidx*NB_H + h)*NB_E) + e + r)*8 + c] = tv;
      }
    }
  } else if (z == 1){
    #pragma unroll
    for (int nt = 0; nt < 4; ++nt){
      const int dk = nt*16 + ll;
      unsigned short* dp = Kb + (((size_t)bidx*NB_H + h)*NB_E + e)*64 + dk;
      #pragma unroll
      for (int r = 0; r < 4; ++r)
        dp[(size_t)r*64] = f2bf(acc[nt][r]);
    }
  } else {
    #pragma unroll
    for (int nt = 0; nt < 4; ++nt){
      const int dv = nt*16 + ll;
      ushort4 ov;
      ov.x = f2bf(acc[nt][0]); ov.y = f2bf(acc[nt][1]);
      ov.z = f2bf(acc[nt][2]); ov.w = f2bf(acc[nt][3]);
      *(ushort4*)(VTb + (((size_t)bidx*NB_H + h)*64 + dv)*NB_E + e) = ov;
    }
  }
}

// ---- FC GEMM: x_out f32 [B,DM,E] = outb @ w_fc^T + residual; 16x32 wave tiles ----
__global__ __launch_bounds__(256, 4) void k_fc(
    const unsigned short* __restrict__ A, const unsigned short* __restrict__ BT,
    float* __restrict__ dst_f, const float* __restrict__ resid)
{
  const int tid = threadIdx.x;
  const int l = tid & 63, wv = tid >> 6;
  const int ll = l & 15, lg = l >> 4;
  const int m0 = blockIdx.x*64 + wv*16;
  const int n0 = blockIdx.y*32;
  const unsigned short* arow = A + (size_t)(m0 + ll)*512 + lg*8;
  const unsigned short* brow = BT + (size_t)(n0 + ll)*512 + lg*8;
  f32x4 acc[2];
  acc[0] = (f32x4){0.f,0.f,0.f,0.f};
  acc[1] = (f32x4){0.f,0.f,0.f,0.f};
  bf16x8 a_c = *(const bf16x8*)(arow);
  bf16x8 b_c0 = *(const bf16x8*)(brow);
  bf16x8 b_c1 = *(const bf16x8*)(brow + 8192);
  #pragma unroll
  for (int ks = 0; ks < 16; ++ks){
    const int kn = (ks + 1) & 15;
    bf16x8 a_n  = *(const bf16x8*)(arow + kn*32);
    bf16x8 b_n0 = *(const bf16x8*)(brow + kn*32);
    bf16x8 b_n1 = *(const bf16x8*)(brow + 8192 + kn*32);
    acc[0] = mfma16(a_c, b_c0, acc[0]);
    acc[1] = mfma16(a_c, b_c1, acc[1]);
    a_c = a_n; b_c0 = b_n0; b_c1 = b_n1;
  }
  const int rbase = m0 + lg*4;
  const int bidx = rbase >> 10;
  const int e = rbase & 1023;
  #pragma unroll
  for (int nt = 0; nt < 2; ++nt){
    const int n = n0 + nt*16 + ll;
    const float* xr = resid + ((size_t)bidx*NB_DM + n)*NB_E + e;
    const float4 rv = *(const float4*)xr;
    const float4 ov = make_float4(acc[nt][0]+rv.x, acc[nt][1]+rv.y,
                                  acc[nt][2]+rv.z, acc[nt][3]+rv.w);
    *(float4*)(dst_f + ((size_t)bidx*NB_DM + n)*NB_E + e) = ov;
  }
}

// ---- fused attention: PERSISTENT. 512 blocks x 512 threads (8 waves), each block
// loops over 2 of the 1024 16-row tiles. Wave w owns 128 j-cols. No-max softmax.
// Unroll-capped loops (code-size discipline). Race-free apeP partials.
// LDS: qr_l [0,384) | reds [512,1024) | d8 [2048,18432) | P bf16 [18432,51200) swizzled
#define D_OFF 2048
#define P_OFF 18432
__global__ __launch_bounds__(512, 4) void k_attn(
    const unsigned short* __restrict__ Q, const unsigned short* __restrict__ K,
    const unsigned short* __restrict__ VT, const float* __restrict__ qr,
    const unsigned char* __restrict__ d8, float* __restrict__ attn_out,
    unsigned short* __restrict__ outb, float* __restrict__ apeP)
{
  __shared__ __align__(16) unsigned char smem[51200];
  unsigned short* plds = (unsigned short*)(smem + P_OFF);
  float* qr_l = (float*)smem;
  float* reds = (float*)(smem + 512);

  const int tid = threadIdx.x;
  const int l = tid & 63, w = tid >> 6;
  const int lg = l >> 4, ll = l & 15;
  const int j0 = w << 7;

  #pragma unroll 1
  for (int t = blockIdx.x; t < 1024; t += 512){
    const int m = t >> 3;
    const int bh = (t & 7)*2 + (m >> 6);       // XCD-locality decode
    const int b = bh >> 3;
    const int it = m & 63;
    const int ib = it << 4;

    // d8 tile (16KB) -> LDS
    const unsigned char* d8g = d8 + ((size_t)b*NB_E + ib)*NB_E;
    const int4 dr0 = ((const int4*)d8g)[tid];
    const int4 dr1 = ((const int4*)(d8g + 8192))[tid];
    ((int4*)(smem + D_OFF))[tid] = dr0;
    ((int4*)(smem + D_OFF + 8192))[tid] = dr1;
    if (tid < 96)
      qr_l[tid] = qr[((size_t)bh*NB_E + ib + (tid/6))*8 + (tid % 6)];

    const unsigned short* Qbp = Q + ((size_t)bh*NB_E + ib)*64;
    const bf16x8 qf0 = *(const bf16x8*)(Qbp + (size_t)ll*64 + lg*8);
    const bf16x8 qf1 = *(const bf16x8*)(Qbp + (size_t)ll*64 + 32 + lg*8);

    // S = (Q/8) K^T over this wave's 128 cols
    f32x4 s[8];
    const unsigned short* Kb = K + (size_t)bh*NB_E*64;
    #pragma unroll 2
    for (int jt = 0; jt < 8; ++jt){
      const size_t krow = (size_t)(j0 + jt*16 + ll)*64;
      const bf16x8 k0 = *(const bf16x8*)(Kb + krow + lg*8);
      const bf16x8 k1 = *(const bf16x8*)(Kb + krow + 32 + lg*8);
      f32x4 acc = {0.f,0.f,0.f,0.f};
      acc = mfma16(qf0, k0, acc);
      acc = mfma16(qf1, k1, acc);
      s[jt] = acc;
    }
    __syncthreads();

    // bias + exp + row-sum (no max subtraction: logits bounded, masked -> 0)
    float rsum[4] = {0.f, 0.f, 0.f, 0.f};
    #pragma unroll 2
    for (int jt = 0; jt < 8; ++jt){
      const int j = j0 + jt*16 + ll;
      #pragma unroll
      for (int r = 0; r < 4; ++r){
        const int il = lg*4 + r;
        const unsigned char c = smem[D_OFF + il*1024 + j];
        const float p = (c < 6)
          ? fast_exp2((s[jt][r] + qr_l[il*6 + c]) * 1.4426950408889634f) : 0.f;
        s[jt][r] = p;
        rsum[r] += p;
      }
    }
    #pragma unroll
    for (int r = 0; r < 4; ++r){
      float sum = rsum[r];
      sum += __shfl_xor(sum, 1);
      sum += __shfl_xor(sum, 2);
      sum += __shfl_xor(sum, 4);
      sum += __shfl_xor(sum, 8);
      if (ll == 0) reds[w*16 + lg*4 + r] = sum;
    }
    __syncthreads();
    float rinv[4];
    #pragma unroll
    for (int r = 0; r < 4; ++r){
      const int il = lg*4 + r;
      float tot = 0.f;
      #pragma unroll
      for (int wv = 0; wv < 8; ++wv) tot += reds[wv*16 + il];
      rinv[r] = 1.0f / (tot + 1e-30f);
    }

    // normalize: P -> bf16 LDS (XOR-swizzled) + race-free ape column partials
    float* apeRow = apeP + (((size_t)bh*64 + it) << 10);
    #pragma unroll 2
    for (int jt = 0; jt < 8; ++jt){
      const int j = j0 + jt*16 + ll;
      float csum = 0.f;
      #pragma unroll
      for (int r = 0; r < 4; ++r){
        const int il = lg*4 + r;
        const float pn = s[jt][r] * rinv[r];
        const int byo = ((il*1024 + j)*2) ^ ((il & 7) << 4);
        plds[byo >> 1] = f2bf(pn);
        csum += pn;
      }
      csum += __shfl_xor(csum, 16);
      csum += __shfl_xor(csum, 32);
      if (l < 16) apeRow[j0 + jt*16 + l] = csum;
    }
    __syncthreads();

    if (w < 4){
      // PV: wave w -> dv chunk [w*16, w*16+16)
      const unsigned short* Vb = VT + ((size_t)bh*64 + w*16 + ll)*NB_E;
      f32x4 o = {0.f,0.f,0.f,0.f};
      #pragma unroll 4
      for (int kk = 0; kk < 32; ++kk){
        const bf16x8 vf = *(const bf16x8*)(Vb + kk*32 + lg*8);
        const int byo = ((ll*2048 + (kk*32 + lg*8)*2)) ^ ((ll & 7) << 4);
        const bf16x8 p = *(const bf16x8*)(smem + P_OFF + byo);
        o = mfma16(p, vf, o);
      }
      const int coln = (bh & 7)*64 + w*16 + ll;
      #pragma unroll
      for (int r = 0; r < 4; ++r){
        const int e0 = ib + lg*4 + r;
        outb[((size_t)b*NB_E + e0)*512 + coln] = f2bf(o[r]);
      }
    } else {
      // store waves: 4 rows each, dense 64-lane f32x4 stores (1KB/instr)
      #pragma unroll
      for (int r2 = 0; r2 < 4; ++r2){
        const int il = (w - 4)*4 + r2;
        float* arow = attn_out + ((size_t)bh*NB_E + ib + il)*NB_E;
        #pragma unroll
        for (int c2 = 0; c2 < 4; ++c2){
          const int col = c2*256 + l*4;
          const int byo = ((il*1024 + col)*2) ^ ((il & 7) << 4);
          const ushort4 pv = *(const ushort4*)(smem + P_OFF + byo);
          f32x4 ov;
          ov[0] = bf2f(pv.x); ov[1] = bf2f(pv.y); ov[2] = bf2f(pv.z); ov[3] = bf2f(pv.w);
          *(f32x4*)(arow + col) = ov;
        }
      }
    }
    __syncthreads();   // protect LDS reuse across persistent iterations
  }
}

// ---- ape reduce: out[b][j] = sum over 512 partial rows / cnt ----
__global__ __launch_bounds__(256) void k_apered(const float* __restrict__ apeP,
    const int* __restrict__ cnt, float* __restrict__ out)
{
  __shared__ float psum[8][32];
  const int b = blockIdx.x;
  const int jg = blockIdx.y;
  const int t = threadIdx.x;
  const int col = jg*32 + (t & 31);
  const int rseg = t >> 5;
  const float* base = apeP + ((size_t)b*512)*1024 + col;
  float acc = 0.f;
  #pragma unroll 8
  for (int i = 0; i < 64; ++i)
    acc += base[(size_t)(rseg + 8*i) << 10];
  psum[rseg][t & 31] = acc;
  __syncthreads();
  if (t < 32){
    float sv = 0.f;
    #pragma unroll
    for (int r2 = 0; r2 < 8; ++r2) sv += psum[r2][t];
    const int j = jg*32 + t;
    const int c = cnt[b*NB_E + j];
    out[b*NB_E + j] = c > 0 ? sv / (float)c : 0.f;
  }
}

extern "C" void kernel_launch(void* const* d_in, const int* in_sizes, int n_in,
                              void* d_out, int out_size, void* d_ws, size_t ws_size,
                              hipStream_t stream)
{
  const float* x        = (const float*)d_in[0];
  const int*   dist     = (const int*)d_in[1];
  const float* base_rpr = (const float*)d_in[2];
  const float* w_q      = (const float*)d_in[3];
  const float* w_k      = (const float*)d_in[4];
  const float* w_v      = (const float*)d_in[5];
  const float* w_fc     = (const float*)d_in[6];
  const float* ln_g     = (const float*)d_in[7];
  const float* ln_b     = (const float*)d_in[8];

  float* x_out    = (float*)d_out;
  float* attn_out = x_out + (size_t)NB_B*NB_DM*NB_E;
  float* ape_out  = attn_out + (size_t)NB_B*NB_H*NB_E*NB_E;

  unsigned char* ws = (unsigned char*)d_ws;
  unsigned short* s_bf   = (unsigned short*)(ws);             // [0, 2MB)
  unsigned short* qn_bf  = (unsigned short*)(ws + 2097152);   // [2MB, 4MB)
  float*          apeP   = (float*)(ws);                      // overlays [0,4MB) after QKV
  unsigned short* wT     = (unsigned short*)(ws + 4194304);   // 4 x 512x512 bf16
  unsigned short* Qb     = (unsigned short*)(ws + 6291456);
  unsigned short* Kb     = (unsigned short*)(ws + 8388608);
  unsigned short* VTb    = (unsigned short*)(ws + 10485760);
  unsigned short* outb   = (unsigned short*)(ws + 12582912);
  float*          qr     = (float*)(ws + 14680064);           // 512KB
  unsigned char*  d8     = ws + 15204352;                     // 2MB
  int*            cnt    = (int*)(ws + 17301504);             // 8KB

  k_zero<<<dim3(1), dim3(512), 0, stream>>>(cnt);

  k_transpose_w<<<dim3(16,16,4), dim3(32,8), 0, stream>>>(w_q, w_k, w_v, w_fc, wT);
  k_transpose_x<<<dim3(32,16,2), dim3(32,8), 0, stream>>>(x, s_bf);
  k_ln<<<dim3(512), dim3(256), 0, stream>>>(s_bf, qn_bf, ln_g, ln_b);
  k_dist<<<dim3(64,2), dim3(256), 0, stream>>>(dist, d8, cnt);

  k_gemm_qkv<<<dim3(32,8,3), dim3(256), 0, stream>>>(qn_bf, s_bf, wT, base_rpr,
                                                     Qb, Kb, VTb, qr);

  k_attn<<<dim3(512), dim3(512), 0, stream>>>(Qb, Kb, VTb, qr, d8,
                                              attn_out, outb, apeP);

  k_fc<<<dim3(32,16), dim3(256), 0, stream>>>(outb, wT + 786432, x_out, x);
  k_apered<<<dim3(2,32), dim3(256), 0, stream>>>(apeP, cnt, ape_out);
}